// Round 3
// baseline (187.501 us; speedup 1.0000x reference)
//
#include <hip/hip_runtime.h>
#include <hip/hip_bf16.h>
#include <stdint.h>

// Problem constants (from reference setup_inputs)
#define BATCH 8
#define TC 2048   // M
#define TQ 1024   // K
#define DD 1024   // N

typedef __attribute__((ext_vector_type(8))) __bf16 bf16x8;
typedef __attribute__((ext_vector_type(16))) float f32x16;

__device__ __forceinline__ ushort f2bf(float f) {
    uint32_t u = __float_as_uint(f);
    uint32_t r = (u + 0x7fffu + ((u >> 16) & 1u)) >> 16;  // RNE
    return (ushort)r;
}

// ---------------------------------------------------------------------------
// Kernel 1 (fused prep): blocks [0,4096) do wave-per-row softmax -> bf16 attn;
// blocks [4096,6144) do 64x64 transpose+cast of qencode -> qt.
// Fused so the two independent ops overlap instead of serializing.
// ---------------------------------------------------------------------------
__global__ __launch_bounds__(256) void prep(const float* __restrict__ sim,
                                            const float* __restrict__ qen,
                                            ushort* __restrict__ attn,
                                            ushort* __restrict__ qt) {
    __shared__ float tile[64][65];
    const int t = threadIdx.x;
    if (blockIdx.x < 4096) {
        // ---- softmax: one wave per row of 1024 ----
        const int wid = t >> 6;
        const int lane = t & 63;
        const int row = blockIdx.x * 4 + wid;
        const float4* src = (const float4*)(sim + (size_t)row * TQ);

        float4 x[4];
        #pragma unroll
        for (int j = 0; j < 4; j++) x[j] = src[lane + 64 * j];

        float m = -INFINITY;
        #pragma unroll
        for (int j = 0; j < 4; j++)
            m = fmaxf(m, fmaxf(fmaxf(x[j].x, x[j].y), fmaxf(x[j].z, x[j].w)));
        #pragma unroll
        for (int o = 32; o >= 1; o >>= 1) m = fmaxf(m, __shfl_xor(m, o));

        const float L2E = 1.4426950408889634f;
        float e[4][4];
        float s = 0.f;
        #pragma unroll
        for (int j = 0; j < 4; j++) {
            e[j][0] = exp2f((x[j].x - m) * L2E);
            e[j][1] = exp2f((x[j].y - m) * L2E);
            e[j][2] = exp2f((x[j].z - m) * L2E);
            e[j][3] = exp2f((x[j].w - m) * L2E);
            s += (e[j][0] + e[j][1]) + (e[j][2] + e[j][3]);
        }
        #pragma unroll
        for (int o = 32; o >= 1; o >>= 1) s += __shfl_xor(s, o);
        const float inv = 1.0f / s;

        ushort4* dst = (ushort4*)(attn + (size_t)row * TQ);
        #pragma unroll
        for (int j = 0; j < 4; j++) {
            ushort4 o4;
            o4.x = f2bf(e[j][0] * inv);
            o4.y = f2bf(e[j][1] * inv);
            o4.z = f2bf(e[j][2] * inv);
            o4.w = f2bf(e[j][3] * inv);
            dst[lane + 64 * j] = o4;
        }
    } else {
        // ---- transpose+cast: qencode [b][q][d] fp32 -> qt [b][d][q] bf16 ----
        const int bid = blockIdx.x - 4096;
        const int b = bid >> 8;             // 256 tiles per batch (16x16)
        const int rem = bid & 255;
        const int q0 = (rem >> 4) * 64;
        const int d0 = (rem & 15) * 64;
        const int r = t >> 4;               // 0..15
        const int c = (t & 15) * 4;         // 0..60

        #pragma unroll
        for (int it = 0; it < 4; it++) {
            float4 v = *(const float4*)(qen + ((size_t)b * TQ + q0 + r + it * 16) * DD + d0 + c);
            tile[r + it * 16][c + 0] = v.x;
            tile[r + it * 16][c + 1] = v.y;
            tile[r + it * 16][c + 2] = v.z;
            tile[r + it * 16][c + 3] = v.w;
        }
        __syncthreads();

        #pragma unroll
        for (int it = 0; it < 4; it++) {
            const int d = (t >> 4) + it * 16;
            const int qq = (t & 15) * 4;
            ushort4 o4;
            o4.x = f2bf(tile[qq + 0][d]);
            o4.y = f2bf(tile[qq + 1][d]);
            o4.z = f2bf(tile[qq + 2][d]);
            o4.w = f2bf(tile[qq + 3][d]);
            *(ushort4*)(qt + ((size_t)b * DD + d0 + d) * TQ + q0 + qq) = o4;
        }
    }
}

// ---------------------------------------------------------------------------
// Kernel 2: batched GEMM  C[b] = A[b] (MxK bf16) x Bt[b]^T (NxK bf16)
// Block tile 256x128, 4 waves each 128x64 via 4x2 of mfma_f32_32x32x16_bf16.
// LDS intensity = 42.7 FLOP/B (> 32 balance point) so LDS BW is off the
// critical path.  Bank-conflict fix: global_load_lds dest is base+lane*16
// (fixed), so we permute the SOURCE chunk (c = x ^ (r&3)); fragment reads
// then spread over all 8 bank-groups instead of aliasing 8-way.
// Grid = 512 blocks = exactly 2/CU (single-shot, all co-resident).
// ---------------------------------------------------------------------------
__global__ __launch_bounds__(256, 2) void gemm_bf16(const ushort* __restrict__ A,
                                                    const ushort* __restrict__ Bt,
                                                    float* __restrict__ C) {
    __shared__ __align__(16) ushort As[256 * 32];   // 16 KiB
    __shared__ __align__(16) ushort Bs[128 * 32];   // 8 KiB

    const int flat = blockIdx.x;
    const int b = flat >> 6;            // batch
    const int rem = flat & 63;          // 8 m-tiles x 8 n-tiles
    const int tm0 = (rem & 7) * 256;
    const int tn0 = (rem >> 3) * 128;

    const ushort* Ab = A + (size_t)b * TC * TQ;
    const ushort* Bb = Bt + (size_t)b * DD * TQ;
    float* Cb = C + (size_t)b * TC * DD;

    const int t = threadIdx.x;
    const int w = t >> 6, lane = t & 63;
    const int row32 = lane & 31, half = lane >> 5;
    const int wm = (w >> 1) * 128, wn = (w & 1) * 64;

    f32x16 acc[4][2];
    #pragma unroll
    for (int i = 0; i < 4; i++)
        #pragma unroll
        for (int j = 0; j < 2; j++)
            #pragma unroll
            for (int r = 0; r < 16; r++) acc[i][j][r] = 0.f;

    for (int kk = 0; kk < TQ; kk += 32) {
        // stage A (256x32 bf16 = 1024 16B-chunks, 4 issues/thread)
        #pragma unroll
        for (int i = 0; i < 4; i++) {
            const int p = i * 256 + w * 64 + lane;
            const int r = p >> 2, x = p & 3;
            const int c = x ^ (r & 3);
            const ushort* ga = Ab + (size_t)(tm0 + r) * TQ + kk + c * 8;
            __builtin_amdgcn_global_load_lds(
                (const __attribute__((address_space(1))) void*)ga,
                (__attribute__((address_space(3))) void*)((char*)As + i * 4096 + w * 1024),
                16, 0, 0);
        }
        // stage B (128x32 bf16 = 512 chunks, 2 issues/thread)
        #pragma unroll
        for (int i = 0; i < 2; i++) {
            const int p = i * 256 + w * 64 + lane;
            const int r = p >> 2, x = p & 3;
            const int c = x ^ (r & 3);
            const ushort* gb = Bb + (size_t)(tn0 + r) * TQ + kk + c * 8;
            __builtin_amdgcn_global_load_lds(
                (const __attribute__((address_space(1))) void*)gb,
                (__attribute__((address_space(3))) void*)((char*)Bs + i * 4096 + w * 1024),
                16, 0, 0);
        }
        __syncthreads();

        #pragma unroll
        for (int s = 0; s < 2; s++) {
            const int c = s * 2 + half;           // k-chunk index 0..3
            bf16x8 af[4], bfr[2];
            #pragma unroll
            for (int mb = 0; mb < 4; mb++) {
                const int r = wm + mb * 32 + row32;
                af[mb] = *(const bf16x8*)&As[r * 32 + (c ^ (r & 3)) * 8];
            }
            #pragma unroll
            for (int nb = 0; nb < 2; nb++) {
                const int r = wn + nb * 32 + row32;
                bfr[nb] = *(const bf16x8*)&Bs[r * 32 + (c ^ (r & 3)) * 8];
            }
            #pragma unroll
            for (int mb = 0; mb < 4; mb++)
                #pragma unroll
                for (int nb = 0; nb < 2; nb++)
                    acc[mb][nb] = __builtin_amdgcn_mfma_f32_32x32x16_bf16(
                        af[mb], bfr[nb], acc[mb][nb], 0, 0, 0);
        }
        __syncthreads();
    }

    // epilogue: 32x32 C/D layout col=lane&31, row=(reg&3)+8*(reg>>2)+4*half
    #pragma unroll
    for (int mb = 0; mb < 4; mb++) {
        #pragma unroll
        for (int nb = 0; nb < 2; nb++) {
            const int colg = tn0 + wn + nb * 32 + row32;
            const int rbase = tm0 + wm + mb * 32 + 4 * half;
            f32x16 v = acc[mb][nb];
            #pragma unroll
            for (int reg = 0; reg < 16; reg++) {
                const int rowg = rbase + (reg & 3) + 8 * (reg >> 2);
                Cb[(size_t)rowg * DD + colg] = v[reg];
            }
        }
    }
}

// ---------------------------------------------------------------------------
extern "C" void kernel_launch(void* const* d_in, const int* in_sizes, int n_in,
                              void* d_out, int out_size, void* d_ws, size_t ws_size,
                              hipStream_t stream) {
    const float* sim = (const float*)d_in[0];   // [8, 2048, 1024]
    const float* qen = (const float*)d_in[1];   // [8, 1024, 1024]
    float* out = (float*)d_out;                 // [8, 2048, 1024]

    ushort* attn = (ushort*)d_ws;                                  // 32 MiB bf16
    ushort* qt = (ushort*)d_ws + (size_t)BATCH * TC * TQ;          // 16 MiB bf16

    prep<<<4096 + 2048, 256, 0, stream>>>(sim, qen, attn, qt);
    gemm_bf16<<<BATCH * 8 * 8, 256, 0, stream>>>(attn, qt, out);
}

// Round 4
// 184.120 us; speedup vs baseline: 1.0184x; 1.0184x over previous
//
#include <hip/hip_runtime.h>
#include <hip/hip_bf16.h>
#include <stdint.h>

// Problem constants (from reference setup_inputs)
#define BATCH 8
#define TC 2048   // M
#define TQ 1024   // K
#define DD 1024   // N

typedef __attribute__((ext_vector_type(8))) __bf16 bf16x8;
typedef __attribute__((ext_vector_type(4))) float f32x4;

__device__ __forceinline__ ushort f2bf(float f) {
    uint32_t u = __float_as_uint(f);
    uint32_t r = (u + 0x7fffu + ((u >> 16) & 1u)) >> 16;  // RNE
    return (ushort)r;
}

// ---------------------------------------------------------------------------
// Kernel 1 (fused prep): blocks [0,4096) do wave-per-row softmax -> bf16 attn;
// blocks [4096,6144) do 64x64 transpose+cast of qencode -> qt.
// ---------------------------------------------------------------------------
__global__ __launch_bounds__(256) void prep(const float* __restrict__ sim,
                                            const float* __restrict__ qen,
                                            ushort* __restrict__ attn,
                                            ushort* __restrict__ qt) {
    __shared__ float tile[64][65];
    const int t = threadIdx.x;
    if (blockIdx.x < 4096) {
        // ---- softmax: one wave per row of 1024 ----
        const int wid = t >> 6;
        const int lane = t & 63;
        const int row = blockIdx.x * 4 + wid;
        const float4* src = (const float4*)(sim + (size_t)row * TQ);

        float4 x[4];
        #pragma unroll
        for (int j = 0; j < 4; j++) x[j] = src[lane + 64 * j];

        float m = -INFINITY;
        #pragma unroll
        for (int j = 0; j < 4; j++)
            m = fmaxf(m, fmaxf(fmaxf(x[j].x, x[j].y), fmaxf(x[j].z, x[j].w)));
        #pragma unroll
        for (int o = 32; o >= 1; o >>= 1) m = fmaxf(m, __shfl_xor(m, o));

        const float L2E = 1.4426950408889634f;
        float e[4][4];
        float s = 0.f;
        #pragma unroll
        for (int j = 0; j < 4; j++) {
            e[j][0] = exp2f((x[j].x - m) * L2E);
            e[j][1] = exp2f((x[j].y - m) * L2E);
            e[j][2] = exp2f((x[j].z - m) * L2E);
            e[j][3] = exp2f((x[j].w - m) * L2E);
            s += (e[j][0] + e[j][1]) + (e[j][2] + e[j][3]);
        }
        #pragma unroll
        for (int o = 32; o >= 1; o >>= 1) s += __shfl_xor(s, o);
        const float inv = 1.0f / s;

        ushort4* dst = (ushort4*)(attn + (size_t)row * TQ);
        #pragma unroll
        for (int j = 0; j < 4; j++) {
            ushort4 o4;
            o4.x = f2bf(e[j][0] * inv);
            o4.y = f2bf(e[j][1] * inv);
            o4.z = f2bf(e[j][2] * inv);
            o4.w = f2bf(e[j][3] * inv);
            dst[lane + 64 * j] = o4;
        }
    } else {
        // ---- transpose+cast: qencode [b][q][d] fp32 -> qt [b][d][q] bf16 ----
        const int bid = blockIdx.x - 4096;
        const int b = bid >> 8;             // 256 tiles per batch (16x16)
        const int rem = bid & 255;
        const int q0 = (rem >> 4) * 64;
        const int d0 = (rem & 15) * 64;
        const int r = t >> 4;               // 0..15
        const int c = (t & 15) * 4;         // 0..60

        #pragma unroll
        for (int it = 0; it < 4; it++) {
            float4 v = *(const float4*)(qen + ((size_t)b * TQ + q0 + r + it * 16) * DD + d0 + c);
            tile[r + it * 16][c + 0] = v.x;
            tile[r + it * 16][c + 1] = v.y;
            tile[r + it * 16][c + 2] = v.z;
            tile[r + it * 16][c + 3] = v.w;
        }
        __syncthreads();

        #pragma unroll
        for (int it = 0; it < 4; it++) {
            const int d = (t >> 4) + it * 16;
            const int qq = (t & 15) * 4;
            ushort4 o4;
            o4.x = f2bf(tile[qq + 0][d]);
            o4.y = f2bf(tile[qq + 1][d]);
            o4.z = f2bf(tile[qq + 2][d]);
            o4.w = f2bf(tile[qq + 3][d]);
            *(ushort4*)(qt + ((size_t)b * DD + d0 + d) * TQ + q0 + qq) = o4;
        }
    }
}

// ---------------------------------------------------------------------------
// Kernel 2: batched GEMM  C[b] = A[b] (MxK bf16) x Bt[b]^T (NxK bf16)
// 128x128 tile, BK=32, 4 waves x (4x4 of 16x16x32 MFMA).
// Bank-conflict-free XOR swizzle keyed on (row>>1)&3:
//   LDS slot (row r, 16B-slot xs) holds global k-chunk  c = xs ^ ((r>>1)&3).
//   - staging (slot -> which global chunk to fetch): c = (lane&3) ^ ((lane>>3)&3)
//   - fragment read (want chunk quad): read slot quad ^ ((l16>>1)&3)
// Any 16 consecutive lanes then land on 8 distinct (parity,chunk) bank-slots
// x2 lanes each = 2-way = free (m136).  1D grid + group swizzle for L2 reuse.
// ---------------------------------------------------------------------------
__global__ __launch_bounds__(256, 2) void gemm_bf16(const ushort* __restrict__ A,
                                                    const ushort* __restrict__ Bt,
                                                    float* __restrict__ C) {
    __shared__ __align__(16) ushort As[128 * 32];
    __shared__ __align__(16) ushort Bs[128 * 32];

    const int flat = blockIdx.x;
    const int b = flat >> 7;          // batch
    const int rem = flat & 127;       // 16 m-tiles x 8 n-tiles
    const int group = rem >> 5;       // 4 groups of 32 blocks
    const int mi_t = group * 4 + (rem & 3);
    const int ni_t = (rem >> 2) & 7;
    const int tm0 = mi_t * 128;
    const int tn0 = ni_t * 128;

    const ushort* Ab = A + (size_t)b * TC * TQ;
    const ushort* Bb = Bt + (size_t)b * DD * TQ;
    float* Cb = C + (size_t)b * TC * DD;

    const int t = threadIdx.x;
    const int w = t >> 6, lane = t & 63;
    const int quad = lane >> 4, l16 = lane & 15;
    const int wm = (w >> 1) * 64, wn = (w & 1) * 64;

    f32x4 acc[4][4];
    #pragma unroll
    for (int i = 0; i < 4; i++)
        #pragma unroll
        for (int j = 0; j < 4; j++) acc[i][j] = (f32x4){0.f, 0.f, 0.f, 0.f};

    // staging: LDS slot index = j*256 + w*64 + lane  (16B slots)
    //   local row r = j*64 + w*16 + (lane>>2), slot-chunk xs = lane&3
    //   fetch global chunk c = xs ^ ((r>>1)&3) = (lane&3) ^ ((lane>>3)&3)
    const int srow = w * 16 + (lane >> 2);
    const int sk = ((lane & 3) ^ ((lane >> 3) & 3)) * 8;   // ushort offset in k

    // fragment read slot-chunk (constant per lane): quad ^ ((l16>>1)&3)
    const int rswz = (quad ^ ((l16 >> 1) & 3)) * 8;

    for (int kk = 0; kk < TQ; kk += 32) {
        #pragma unroll
        for (int j = 0; j < 2; j++) {
            const ushort* ga = Ab + (size_t)(tm0 + j * 64 + srow) * TQ + kk + sk;
            const ushort* gb = Bb + (size_t)(tn0 + j * 64 + srow) * TQ + kk + sk;
            char* la = (char*)As + j * 4096 + w * 1024;
            char* lb = (char*)Bs + j * 4096 + w * 1024;
            __builtin_amdgcn_global_load_lds(
                (const __attribute__((address_space(1))) void*)ga,
                (__attribute__((address_space(3))) void*)la, 16, 0, 0);
            __builtin_amdgcn_global_load_lds(
                (const __attribute__((address_space(1))) void*)gb,
                (__attribute__((address_space(3))) void*)lb, 16, 0, 0);
        }
        __syncthreads();

        bf16x8 af[4], bfr[4];
        #pragma unroll
        for (int mi = 0; mi < 4; mi++)
            af[mi] = *(const bf16x8*)&As[(wm + mi * 16 + l16) * 32 + rswz];
        #pragma unroll
        for (int ni = 0; ni < 4; ni++)
            bfr[ni] = *(const bf16x8*)&Bs[(wn + ni * 16 + l16) * 32 + rswz];

        #pragma unroll
        for (int mi = 0; mi < 4; mi++)
            #pragma unroll
            for (int ni = 0; ni < 4; ni++)
                acc[mi][ni] = __builtin_amdgcn_mfma_f32_16x16x32_bf16(
                    af[mi], bfr[ni], acc[mi][ni], 0, 0, 0);
        __syncthreads();
    }

    // epilogue: C/D layout col=lane&15, row=quad*4+reg
    #pragma unroll
    for (int mi = 0; mi < 4; mi++) {
        const int r0 = tm0 + wm + mi * 16 + quad * 4;
        #pragma unroll
        for (int ni = 0; ni < 4; ni++) {
            const int c = tn0 + wn + ni * 16 + l16;
            f32x4 v = acc[mi][ni];
            #pragma unroll
            for (int r = 0; r < 4; r++) Cb[(size_t)(r0 + r) * DD + c] = v[r];
        }
    }
}

// ---------------------------------------------------------------------------
extern "C" void kernel_launch(void* const* d_in, const int* in_sizes, int n_in,
                              void* d_out, int out_size, void* d_ws, size_t ws_size,
                              hipStream_t stream) {
    const float* sim = (const float*)d_in[0];   // [8, 2048, 1024]
    const float* qen = (const float*)d_in[1];   // [8, 1024, 1024]
    float* out = (float*)d_out;                 // [8, 2048, 1024]

    ushort* attn = (ushort*)d_ws;                                  // 32 MiB bf16
    ushort* qt = (ushort*)d_ws + (size_t)BATCH * TC * TQ;          // 16 MiB bf16

    prep<<<4096 + 2048, 256, 0, stream>>>(sim, qen, attn, qt);
    gemm_bf16<<<BATCH * (TC / 128) * (DD / 128), 256, 0, stream>>>(attn, qt, out);
}

// Round 5
// 174.644 us; speedup vs baseline: 1.0736x; 1.0543x over previous
//
#include <hip/hip_runtime.h>
#include <hip/hip_bf16.h>
#include <stdint.h>

// Problem constants (from reference setup_inputs)
#define BATCH 8
#define TC 2048   // M
#define TQ 1024   // K
#define DD 1024   // N

typedef __attribute__((ext_vector_type(8))) __bf16 bf16x8;
typedef __attribute__((ext_vector_type(4))) float f32x4;

__device__ __forceinline__ ushort f2bf(float f) {
    uint32_t u = __float_as_uint(f);
    uint32_t r = (u + 0x7fffu + ((u >> 16) & 1u)) >> 16;  // RNE
    return (ushort)r;
}

// ---------------------------------------------------------------------------
// Kernel 1 (fused prep): blocks [0,4096) do wave-per-row softmax -> bf16 attn;
// blocks [4096,6144) do 64x64 transpose+cast of qencode -> qt.
// ---------------------------------------------------------------------------
__global__ __launch_bounds__(256) void prep(const float* __restrict__ sim,
                                            const float* __restrict__ qen,
                                            ushort* __restrict__ attn,
                                            ushort* __restrict__ qt) {
    __shared__ float tile[64][65];
    const int t = threadIdx.x;
    if (blockIdx.x < 4096) {
        // ---- softmax: one wave per row of 1024 ----
        const int wid = t >> 6;
        const int lane = t & 63;
        const int row = blockIdx.x * 4 + wid;
        const float4* src = (const float4*)(sim + (size_t)row * TQ);

        float4 x[4];
        #pragma unroll
        for (int j = 0; j < 4; j++) x[j] = src[lane + 64 * j];

        float m = -INFINITY;
        #pragma unroll
        for (int j = 0; j < 4; j++)
            m = fmaxf(m, fmaxf(fmaxf(x[j].x, x[j].y), fmaxf(x[j].z, x[j].w)));
        #pragma unroll
        for (int o = 32; o >= 1; o >>= 1) m = fmaxf(m, __shfl_xor(m, o));

        const float L2E = 1.4426950408889634f;
        float e[4][4];
        float s = 0.f;
        #pragma unroll
        for (int j = 0; j < 4; j++) {
            e[j][0] = exp2f((x[j].x - m) * L2E);
            e[j][1] = exp2f((x[j].y - m) * L2E);
            e[j][2] = exp2f((x[j].z - m) * L2E);
            e[j][3] = exp2f((x[j].w - m) * L2E);
            s += (e[j][0] + e[j][1]) + (e[j][2] + e[j][3]);
        }
        #pragma unroll
        for (int o = 32; o >= 1; o >>= 1) s += __shfl_xor(s, o);
        const float inv = 1.0f / s;

        ushort4* dst = (ushort4*)(attn + (size_t)row * TQ);
        #pragma unroll
        for (int j = 0; j < 4; j++) {
            ushort4 o4;
            o4.x = f2bf(e[j][0] * inv);
            o4.y = f2bf(e[j][1] * inv);
            o4.z = f2bf(e[j][2] * inv);
            o4.w = f2bf(e[j][3] * inv);
            dst[lane + 64 * j] = o4;
        }
    } else {
        // ---- transpose+cast: qencode [b][q][d] fp32 -> qt [b][d][q] bf16 ----
        const int bid = blockIdx.x - 4096;
        const int b = bid >> 8;             // 256 tiles per batch (16x16)
        const int rem = bid & 255;
        const int q0 = (rem >> 4) * 64;
        const int d0 = (rem & 15) * 64;
        const int r = t >> 4;               // 0..15
        const int c = (t & 15) * 4;         // 0..60

        #pragma unroll
        for (int it = 0; it < 4; it++) {
            float4 v = *(const float4*)(qen + ((size_t)b * TQ + q0 + r + it * 16) * DD + d0 + c);
            tile[r + it * 16][c + 0] = v.x;
            tile[r + it * 16][c + 1] = v.y;
            tile[r + it * 16][c + 2] = v.z;
            tile[r + it * 16][c + 3] = v.w;
        }
        __syncthreads();

        #pragma unroll
        for (int it = 0; it < 4; it++) {
            const int d = (t >> 4) + it * 16;
            const int qq = (t & 15) * 4;
            ushort4 o4;
            o4.x = f2bf(tile[qq + 0][d]);
            o4.y = f2bf(tile[qq + 1][d]);
            o4.z = f2bf(tile[qq + 2][d]);
            o4.w = f2bf(tile[qq + 3][d]);
            *(ushort4*)(qt + ((size_t)b * DD + d0 + d) * TQ + q0 + qq) = o4;
        }
    }
}

// ---------------------------------------------------------------------------
// Kernel 2: batched GEMM  C[b] = A[b] (MxK bf16) x Bt[b]^T (NxK bf16)
// 128x128 tile, BK=64 (two 32-k substeps per staging), 4 waves x (4x4 of
// 16x16x32 MFMA).  Halves barrier count / vmcnt(0) drains vs BK=32 while
// LDS stays 32 KiB (4 blocks/CU residency kept, unlike BK=128 / m132).
// Bank-conflict-free XOR swizzle keyed on row&7 (rows are 128 B = 8 chunks):
//   LDS slot (row r, 16B-slot xs) holds global k-chunk  c = xs ^ (r&7)
//   - staging source chunk: (lane&7) ^ (lane>>3)   [per-lane constant]
//   - fragment read slot:   (s*4+quad) ^ (l16&7)
//   any 16-lane read phase covers all 32 banks exactly 2-way = free (m136).
// ---------------------------------------------------------------------------
__global__ __launch_bounds__(256, 2) void gemm_bf16(const ushort* __restrict__ A,
                                                    const ushort* __restrict__ Bt,
                                                    float* __restrict__ C) {
    __shared__ __align__(16) ushort As[128 * 64];   // 16 KiB
    __shared__ __align__(16) ushort Bs[128 * 64];   // 16 KiB

    const int flat = blockIdx.x;
    const int b = flat >> 7;          // batch
    const int rem = flat & 127;       // 16 m-tiles x 8 n-tiles
    const int group = rem >> 5;       // 4 groups of 32 blocks
    const int mi_t = group * 4 + (rem & 3);
    const int ni_t = (rem >> 2) & 7;
    const int tm0 = mi_t * 128;
    const int tn0 = ni_t * 128;

    const ushort* Ab = A + (size_t)b * TC * TQ;
    const ushort* Bb = Bt + (size_t)b * DD * TQ;
    float* Cb = C + (size_t)b * TC * DD;

    const int t = threadIdx.x;
    const int w = t >> 6, lane = t & 63;
    const int quad = lane >> 4, l16 = lane & 15;
    const int wm = (w >> 1) * 64, wn = (w & 1) * 64;

    f32x4 acc[4][4];
    #pragma unroll
    for (int i = 0; i < 4; i++)
        #pragma unroll
        for (int j = 0; j < 4; j++) acc[i][j] = (f32x4){0.f, 0.f, 0.f, 0.f};

    // staging: chunk idx = i*256 + w*64 + lane; row = idx>>3 = i*32+w*8+(lane>>3)
    // slot-chunk xs = lane&7; fetch global chunk c = xs ^ (row&7)
    const int srow = w * 8 + (lane >> 3);
    const int sk = ((lane & 7) ^ (lane >> 3)) * 8;   // ushort offset in k

    // fragment read: row = frag_base + l16 (frag_base % 16 == 0), so row&7 = l16&7
    const int rkey = l16 & 7;

    for (int kk = 0; kk < TQ; kk += 64) {
        #pragma unroll
        for (int i = 0; i < 4; i++) {
            const ushort* ga = Ab + (size_t)(tm0 + i * 32 + srow) * TQ + kk + sk;
            const ushort* gb = Bb + (size_t)(tn0 + i * 32 + srow) * TQ + kk + sk;
            char* la = (char*)As + i * 4096 + w * 1024;
            char* lb = (char*)Bs + i * 4096 + w * 1024;
            __builtin_amdgcn_global_load_lds(
                (const __attribute__((address_space(1))) void*)ga,
                (__attribute__((address_space(3))) void*)la, 16, 0, 0);
            __builtin_amdgcn_global_load_lds(
                (const __attribute__((address_space(1))) void*)gb,
                (__attribute__((address_space(3))) void*)lb, 16, 0, 0);
        }
        __syncthreads();

        #pragma unroll
        for (int s = 0; s < 2; s++) {
            const int rswz = ((s * 4 + quad) ^ rkey) * 8;   // ushort offset
            bf16x8 af[4], bfr[4];
            #pragma unroll
            for (int mi = 0; mi < 4; mi++)
                af[mi] = *(const bf16x8*)&As[(wm + mi * 16 + l16) * 64 + rswz];
            #pragma unroll
            for (int ni = 0; ni < 4; ni++)
                bfr[ni] = *(const bf16x8*)&Bs[(wn + ni * 16 + l16) * 64 + rswz];

            #pragma unroll
            for (int mi = 0; mi < 4; mi++)
                #pragma unroll
                for (int ni = 0; ni < 4; ni++)
                    acc[mi][ni] = __builtin_amdgcn_mfma_f32_16x16x32_bf16(
                        af[mi], bfr[ni], acc[mi][ni], 0, 0, 0);
        }
        __syncthreads();
    }

    // epilogue: C/D layout col=lane&15, row=quad*4+reg
    #pragma unroll
    for (int mi = 0; mi < 4; mi++) {
        const int r0 = tm0 + wm + mi * 16 + quad * 4;
        #pragma unroll
        for (int ni = 0; ni < 4; ni++) {
            const int c = tn0 + wn + ni * 16 + l16;
            f32x4 v = acc[mi][ni];
            #pragma unroll
            for (int r = 0; r < 4; r++) Cb[(size_t)(r0 + r) * DD + c] = v[r];
        }
    }
}

// ---------------------------------------------------------------------------
extern "C" void kernel_launch(void* const* d_in, const int* in_sizes, int n_in,
                              void* d_out, int out_size, void* d_ws, size_t ws_size,
                              hipStream_t stream) {
    const float* sim = (const float*)d_in[0];   // [8, 2048, 1024]
    const float* qen = (const float*)d_in[1];   // [8, 1024, 1024]
    float* out = (float*)d_out;                 // [8, 2048, 1024]

    ushort* attn = (ushort*)d_ws;                                  // 32 MiB bf16
    ushort* qt = (ushort*)d_ws + (size_t)BATCH * TC * TQ;          // 16 MiB bf16

    prep<<<4096 + 2048, 256, 0, stream>>>(sim, qen, attn, qt);
    gemm_bf16<<<BATCH * (TC / 128) * (DD / 128), 256, 0, stream>>>(attn, qt, out);
}